// Round 6
// baseline (34.674 us; speedup 1.0000x reference)
//
#include <hip/hip_runtime.h>

#define NC 8                   // NUM_CLASSES
#define NB 4                   // batch size
#define XBLK 256               // blocks per batch -> 1024 blocks = 4/CU = 16 waves/CU
#define TPB 256
#define GRID (XBLK * NB)
#define STRIDE (XBLK * TPB)    // 65536 int4 vectors per sweep
#define NCNT (NB * 3 * NC)     // 96 global counters; ws[96] = ticket

// Fused: per-(batch,class) histogram -> device-scope atomic accumulate ->
// last-arriving block (atomic ticket) computes the 8 outputs. All cross-block
// communication is via device-scope atomics (coherent across XCDs) -- no
// threadfence needed: __syncthreads drains vmcnt, ordering each block's
// counter atomics before its ticket atomic.
__global__ void __launch_bounds__(TPB) dice_fused_kernel(
    const int* __restrict__ pred, const int* __restrict__ label,
    unsigned int* __restrict__ ws, float* __restrict__ out, int nvec_per_batch)
{
    const int xblk = blockIdx.x & (XBLK - 1);
    const int b    = blockIdx.x >> 8;
    const int4* p4 = reinterpret_cast<const int4*>(pred) + (size_t)b * nvec_per_batch;
    const int4* l4 = reinterpret_cast<const int4*>(label) + (size_t)b * nvec_per_batch;

    // 8 classes x 8-bit fields in one 64-bit accumulator. Per-thread element
    // count is 32 for the target shape -- below the 255 field cap.
    unsigned long long packP = 0, packL = 0, packI = 0;

    int i = xblk * TPB + (int)threadIdx.x;

    // Batch-issue 8 independent dwordx4 loads (4 pred + 4 label) per pass;
    // 2 passes for the target shape. Tail loop unused for the target shape.
    for (; i + 3 * STRIDE < nvec_per_batch; i += 4 * STRIDE) {
        int4 pv[4], lv[4];
        #pragma unroll
        for (int u = 0; u < 4; ++u) {
            pv[u] = p4[i + u * STRIDE];
            lv[u] = l4[i + u * STRIDE];
        }
        #pragma unroll
        for (int u = 0; u < 4; ++u) {
            int pe[4] = {pv[u].x, pv[u].y, pv[u].z, pv[u].w};
            int le[4] = {lv[u].x, lv[u].y, lv[u].z, lv[u].w};
            #pragma unroll
            for (int j = 0; j < 4; ++j) {
                unsigned long long sp = 1ULL << (pe[j] * 8);
                unsigned long long sl = 1ULL << (le[j] * 8);
                packP += sp;
                packL += sl;
                packI += (pe[j] == le[j]) ? sp : 0ULL;
            }
        }
    }
    for (; i < nvec_per_batch; i += STRIDE) {
        int4 pv = p4[i];
        int4 lv = l4[i];
        int pe[4] = {pv.x, pv.y, pv.z, pv.w};
        int le[4] = {lv.x, lv.y, lv.z, lv.w};
        #pragma unroll
        for (int j = 0; j < 4; ++j) {
            unsigned long long sp = 1ULL << (pe[j] * 8);
            unsigned long long sl = 1ULL << (le[j] * 8);
            packP += sp;
            packL += sl;
            packI += (pe[j] == le[j]) ? sp : 0ULL;
        }
    }

    // Unpack to 24 per-class counts (static indexing after unroll).
    unsigned cnt[3 * NC];
    #pragma unroll
    for (int c = 0; c < NC; ++c) {
        cnt[c]          = (unsigned)((packP >> (8 * c)) & 0xFFULL);
        cnt[NC + c]     = (unsigned)((packL >> (8 * c)) & 0xFFULL);
        cnt[2 * NC + c] = (unsigned)((packI >> (8 * c)) & 0xFFULL);
    }

    // Wave64 tree reduction.
    #pragma unroll
    for (int k = 0; k < 3 * NC; ++k) {
        #pragma unroll
        for (int off = 32; off > 0; off >>= 1)
            cnt[k] += __shfl_down(cnt[k], off, 64);
    }

    // Cross-wave reduction in LDS (4 waves).
    __shared__ unsigned s[3 * NC];
    if (threadIdx.x < 3 * NC) s[threadIdx.x] = 0;
    __syncthreads();
    if ((threadIdx.x & 63) == 0) {
        #pragma unroll
        for (int k = 0; k < 3 * NC; ++k)
            atomicAdd(&s[k], cnt[k]);
    }
    __syncthreads();

    // Device-scope atomic accumulation of this block's 24 partials.
    if (threadIdx.x < 3 * NC)
        atomicAdd(&ws[b * 3 * NC + threadIdx.x], s[threadIdx.x]);
    __syncthreads();   // s_waitcnt vmcnt(0): counter atomics complete before ticket

    // Ticket: exactly one block sees old == GRID-1, strictly after every
    // block's counter atomics have reached the device-coherent point.
    __shared__ int last;
    if (threadIdx.x == 0)
        last = (atomicAdd(&ws[NCNT], 1u) == GRID - 1) ? 1 : 0;
    __syncthreads();
    if (!last) return;

    // Last block: atomic read-back of the 96 totals (coherent), 8 dice means.
    __shared__ float tot[NCNT];
    if (threadIdx.x < NCNT)
        tot[threadIdx.x] = (float)atomicAdd(&ws[threadIdx.x], 0u);
    __syncthreads();

    if (threadIdx.x < NC) {
        const int c = threadIdx.x;
        float acc = 0.0f;
        #pragma unroll
        for (int bb = 0; bb < NB; ++bb) {
            float P = tot[bb * 3 * NC + c];
            float L = tot[bb * 3 * NC + NC + c];
            float I = tot[bb * 3 * NC + 2 * NC + c];
            acc += 2.0f * I / (P + L + 1e-10f);
        }
        out[c] = acc * (1.0f / NB);
    }
}

extern "C" void kernel_launch(void* const* d_in, const int* in_sizes, int n_in,
                              void* d_out, int out_size, void* d_ws, size_t ws_size,
                              hipStream_t stream)
{
    const int* pred  = (const int*)d_in[0];
    const int* label = (const int*)d_in[1];
    float* out = (float*)d_out;
    unsigned int* ws = (unsigned int*)d_ws;

    const int n = in_sizes[0];          // 4*1*128*128*128 = 8388608
    const int per_batch = n / NB;       // 2097152
    int nvec = per_batch / 4;           // 524288 int4 vectors per batch

    // Zero 96 counters + ticket (388 B).
    hipMemsetAsync(ws, 0, (size_t)(NCNT + 1) * sizeof(unsigned int), stream);

    dice_fused_kernel<<<dim3(GRID), dim3(TPB), 0, stream>>>(pred, label, ws, out, nvec);
}

// Round 7
// 20.881 us; speedup vs baseline: 1.6606x; 1.6606x over previous
//
#include <hip/hip_runtime.h>

#define NC 8                   // NUM_CLASSES
#define NB 4                   // batch size
#define XBLK 512               // blocks per batch -> grid (512,4) = 2048 blocks = 8/CU = 32 waves/CU
#define TPB 256
#define STRIDE (XBLK * TPB)    // 131072 int4 vectors per sweep

// Per-(batch,class) counts: P = #{pred==c}, L = #{label==c}, I = #{pred==label==c}.
// Each block writes 24 partials to ws[(b*24+k)*XBLK + xblk] (transposed so the
// finalize reads coalesce). No atomics on global, no ws init needed.
// NVEC_C != 0 makes the trip count compile-time (single batched iteration,
// tail loop elided for the bench shape).
template<int NVEC_C>
__global__ void __launch_bounds__(TPB) dice_count_kernel(
    const int* __restrict__ pred, const int* __restrict__ label,
    unsigned int* __restrict__ ws, int nvec_rt)
{
    const int nvec = NVEC_C ? NVEC_C : nvec_rt;
    const int xblk = blockIdx.x;
    const int b    = blockIdx.y;
    const int4* p4 = reinterpret_cast<const int4*>(pred) + (size_t)b * nvec;
    const int4* l4 = reinterpret_cast<const int4*>(label) + (size_t)b * nvec;

    // 8 classes x 8-bit fields in one 64-bit accumulator. Per-thread element
    // count is 16 for the bench shape -- far below the 255 field cap.
    unsigned long long packP = 0, packL = 0, packI = 0;

    int i = xblk * TPB + (int)threadIdx.x;

    // Batch-issue 8 independent dwordx4 loads (4 pred + 4 label), then consume.
    // For NVEC_C=524288 this runs exactly once and the tail loop disappears.
    for (; i + 3 * STRIDE < nvec; i += 4 * STRIDE) {
        int4 pv[4], lv[4];
        #pragma unroll
        for (int u = 0; u < 4; ++u) {
            pv[u] = p4[i + u * STRIDE];
            lv[u] = l4[i + u * STRIDE];
        }
        #pragma unroll
        for (int u = 0; u < 4; ++u) {
            int pe[4] = {pv[u].x, pv[u].y, pv[u].z, pv[u].w};
            int le[4] = {lv[u].x, lv[u].y, lv[u].z, lv[u].w};
            #pragma unroll
            for (int j = 0; j < 4; ++j) {
                unsigned long long sp = 1ULL << (pe[j] * 8);
                unsigned long long sl = 1ULL << (le[j] * 8);
                packP += sp;
                packL += sl;
                packI += (pe[j] == le[j]) ? sp : 0ULL;
            }
        }
    }
    for (; i < nvec; i += STRIDE) {   // generic tail (elided when NVEC_C set)
        int4 pv = p4[i];
        int4 lv = l4[i];
        int pe[4] = {pv.x, pv.y, pv.z, pv.w};
        int le[4] = {lv.x, lv.y, lv.z, lv.w};
        #pragma unroll
        for (int j = 0; j < 4; ++j) {
            unsigned long long sp = 1ULL << (pe[j] * 8);
            unsigned long long sl = 1ULL << (le[j] * 8);
            packP += sp;
            packL += sl;
            packI += (pe[j] == le[j]) ? sp : 0ULL;
        }
    }

    // Split each byte-pack into 4 u32s holding 2 x u16 fields:
    //   d[0]=classes{0,2} d[1]={1,3} d[2]={4,6} d[3]={5,7}  (lo16, hi16)
    // Wave-sum per field max = 64 lanes * 16 elems = 1024 < 65536: carry-safe.
    unsigned e[12];
    {
        unsigned long long pk[3] = {packP, packL, packI};
        #pragma unroll
        for (int w = 0; w < 3; ++w) {
            unsigned lo = (unsigned)pk[w], hi = (unsigned)(pk[w] >> 32);
            e[w * 4 + 0] = lo & 0x00FF00FFu;
            e[w * 4 + 1] = (lo >> 8) & 0x00FF00FFu;
            e[w * 4 + 2] = hi & 0x00FF00FFu;
            e[w * 4 + 3] = (hi >> 8) & 0x00FF00FFu;
        }
    }

    // Wave64 tree reduction on 12 packed values (72 shuffles vs 144 unpacked).
    #pragma unroll
    for (int k = 0; k < 12; ++k) {
        #pragma unroll
        for (int off = 32; off > 0; off >>= 1)
            e[k] += __shfl_down(e[k], off, 64);
    }

    // Cross-wave combine of packed values (4 waves: max 4096/field, still u16-safe),
    // then unpack to the 24-counter transposed layout.
    __shared__ unsigned sp12[12];
    if (threadIdx.x < 12) sp12[threadIdx.x] = 0;
    __syncthreads();
    if ((threadIdx.x & 63) == 0) {
        #pragma unroll
        for (int k = 0; k < 12; ++k)
            atomicAdd(&sp12[k], e[k]);
    }
    __syncthreads();
    if (threadIdx.x < 12) {
        unsigned v  = sp12[threadIdx.x];
        int which   = threadIdx.x >> 2;          // 0=P, 1=L, 2=I
        int q       = threadIdx.x & 3;
        int clo     = (q & 1) + 4 * (q >> 1);    // lo16 class
        int base    = b * 3 * NC + which * NC;
        ws[(size_t)(base + clo)     * XBLK + xblk] = v & 0xFFFFu;
        ws[(size_t)(base + clo + 2) * XBLK + xblk] = v >> 16;
    }
}

// 8 blocks (one per class) x 256 threads (wave = batch). Each wave reduces the
// class's P/L/I rows (512 partials each, 2 uint4 per lane per row), computes
// dice[b]; thread 0 averages over batches.
__global__ void __launch_bounds__(TPB) dice_final_kernel(
    const unsigned int* __restrict__ ws, float* __restrict__ out)
{
    const int c    = blockIdx.x;
    const int b    = threadIdx.x >> 6;
    const int lane = threadIdx.x & 63;
    const uint4* base = reinterpret_cast<const uint4*>(ws);

    unsigned sums[3];
    uint4 v[3][2];
    #pragma unroll
    for (int k = 0; k < 3; ++k) {
        const uint4* row = base + (size_t)(b * 3 * NC + k * NC + c) * (XBLK / 4);
        v[k][0] = row[lane];
        v[k][1] = row[lane + 64];
    }
    #pragma unroll
    for (int k = 0; k < 3; ++k) {
        sums[k] = v[k][0].x + v[k][0].y + v[k][0].z + v[k][0].w
                + v[k][1].x + v[k][1].y + v[k][1].z + v[k][1].w;
        #pragma unroll
        for (int off = 32; off > 0; off >>= 1)
            sums[k] += __shfl_down(sums[k], off, 64);
    }

    __shared__ float dice[NB];
    if (lane == 0) {
        float P = (float)sums[0], L = (float)sums[1], I = (float)sums[2];
        dice[b] = 2.0f * I / (P + L + 1e-10f);
    }
    __syncthreads();
    if (threadIdx.x == 0)
        out[c] = 0.25f * (dice[0] + dice[1] + dice[2] + dice[3]);
}

extern "C" void kernel_launch(void* const* d_in, const int* in_sizes, int n_in,
                              void* d_out, int out_size, void* d_ws, size_t ws_size,
                              hipStream_t stream)
{
    const int* pred  = (const int*)d_in[0];
    const int* label = (const int*)d_in[1];
    float* out = (float*)d_out;
    unsigned int* ws = (unsigned int*)d_ws;

    const int n = in_sizes[0];          // 4*1*128*128*128 = 8388608
    const int per_batch = n / NB;       // 2097152
    int nvec = per_batch / 4;           // 524288 int4 vectors per batch

    if (nvec == 524288)
        dice_count_kernel<524288><<<dim3(XBLK, NB), dim3(TPB), 0, stream>>>(pred, label, ws, nvec);
    else
        dice_count_kernel<0><<<dim3(XBLK, NB), dim3(TPB), 0, stream>>>(pred, label, ws, nvec);
    dice_final_kernel<<<dim3(NC), dim3(TPB), 0, stream>>>(ws, out);
}